// Round 8
// baseline (97.824 us; speedup 1.0000x reference)
//
#include <hip/hip_runtime.h>
#include <math.h>

#define NCONST 100
#define NF     16

typedef _Float16 f16;
typedef _Float16 f16x8 __attribute__((ext_vector_type(8)));
typedef _Float16 f16x4 __attribute__((ext_vector_type(4)));
typedef float    f32x16 __attribute__((ext_vector_type(16)));

// ---------------- K1: BN + layer-1 projections -> Pr/Ps (f16) in ws ----------------
// item = (n, sel, oq): 1600 per batch element; grid (7, B), 256 threads.
// Pr row has frb1 folded in; Ps bias-free. Row = 40 halves (80 B); cols 30,31
// written ZERO (K=32 MFMA pad), cols 32..39 never read.
__global__ __launch_bounds__(256) void k1_proj(
    const float* __restrict__ x,
    const float* __restrict__ bn_g, const float* __restrict__ bn_b,
    const float* __restrict__ bn_m, const float* __restrict__ bn_v,
    const float* __restrict__ frw1, const float* __restrict__ frb1,
    f16* __restrict__ prps)
{
    const int b  = blockIdx.y;
    const int it = blockIdx.x * 256 + threadIdx.x;
    if (it >= NCONST * 16) return;
    const int n = it >> 4, rem = it & 15, sel = rem >> 3, oq = rem & 7, o0 = oq * 4;

    const float* xr = x + ((size_t)b * NCONST + n) * NF;
    float xs[16];
    #pragma unroll
    for (int f = 0; f < 16; ++f) {
        float s = bn_g[f] * rsqrtf(bn_v[f] + 1e-3f);
        xs[f] = (xr[f] - bn_m[f]) * s + bn_b[f];
    }
    float acc0 = (!sel) ? frb1[o0 + 0] : 0.f;
    float acc1 = (!sel) ? frb1[o0 + 1] : 0.f;
    float acc2 = (!sel && oq < 7) ? frb1[o0 + 2] : 0.f;
    float acc3 = (!sel && oq < 7) ? frb1[o0 + 3] : 0.f;
    const float* wbase = frw1 + sel * 16 * 30;
    const int wcol2 = (oq < 7) ? o0 + 2 : 28;   // clamp keeps loads in-bounds
    #pragma unroll
    for (int f = 0; f < 16; ++f) {
        const float* wr = wbase + f * 30;
        float2 wa = *(const float2*)(wr + o0);
        float2 wb = *(const float2*)(wr + wcol2);
        acc0 = fmaf(xs[f], wa.x, acc0);
        acc1 = fmaf(xs[f], wa.y, acc1);
        acc2 = fmaf(xs[f], wb.x, acc2);
        acc3 = fmaf(xs[f], wb.y, acc3);
    }
    f16x4 hv;
    hv[0] = (f16)acc0; hv[1] = (f16)acc1;
    hv[2] = (oq < 7) ? (f16)acc2 : (f16)0.f;   // cols 30,31 -> 0
    hv[3] = (oq < 7) ? (f16)acc3 : (f16)0.f;
    *(f16x4*)(prps + (size_t)b * 8192 + sel * 4096 + n * 40 + o0) = hv;
}

// ---------------- K2: edge MLP via 32x32x16 MFMA ----------------
// grid (4, B): block = (receiver-quarter, b), 256 threads = 4 waves.
// Tile = (receiver i, 32 senders). Per tile: 2 ds_read_b128 (Ps halves) ->
// h1 -> MFMA1a/b (C-chained, b2 folded into C) -> pack+2 shfl_xor redistribute
// -> MFMA2 -> register accumulate. Tile 3 holds senders 96..98 (rows 0..2
// valid, rest masked at racc). One barrier per kernel (after staging).
__global__ __launch_bounds__(256, 4) void k2_edge(
    const f16* __restrict__ prps,
    const float* __restrict__ frw2, const float* __restrict__ frb2,
    const float* __restrict__ frw3, const float* __restrict__ frb3,
    float* __restrict__ agg)
{
    __shared__ f16 P[8192];   // 16 KB: Pr rows @ byte i*80, Ps @ 8192 + j*80

    const int rb  = blockIdx.x;
    const int b   = blockIdx.y;
    const int tid = threadIdx.x;
    {
        const float4* src = (const float4*)(prps + (size_t)b * 8192);
        float4* dst = (float4*)P;
        #pragma unroll
        for (int k = 0; k < 4; ++k) dst[tid + 256 * k] = src[tid + 256 * k];
    }
    __syncthreads();
    const char* Pb = (const char*)P;

    const int l  = tid & 63;
    const int wv = tid >> 6;      // wave 0..3
    const int e  = l & 31;
    const int hi = l >> 5;

    const int eC  = (e < 15) ? e : 14;
    const int eC3 = (e < 6)  ? e : 5;

    // Weight fragments (VGPR-resident). A-frag: row=l&31, k=(l>>5)*8+m.
    f16x8 bf1a, bf1b, bf2;
    #pragma unroll
    for (int m = 0; m < 8; ++m) {
        int ka  = hi * 8 + m;          // 0..15
        int kb_ = 16 + ka;             // 16..31
        float wa = frw2[ka * 15 + eC];
        float wb = frw2[((kb_ < 30) ? kb_ : 29) * 15 + eC];
        float w3 = frw3[((ka < 15) ? ka : 14) * 6 + eC3];
        bf1a[m] = (e < 15)              ? (f16)wa : (f16)0.f;
        bf1b[m] = (e < 15 && kb_ < 30)  ? (f16)wb : (f16)0.f;
        bf2[m]  = (e < 6  && ka  < 15)  ? (f16)w3 : (f16)0.f;
    }
    // b2 folded into MFMA C: C/D row = (r&3)+8*(r>>2)+4*hi, col = l&31.
    f32x16 Cb2, cz;
    #pragma unroll
    for (int r = 0; r < 16; ++r) {
        int row = (r & 3) + 8 * (r >> 2) + 4 * hi;
        Cb2[r] = (row < 15) ? frb2[(row < 15) ? row : 14] : 0.f;
        cz[r] = 0.f;
    }
    const float b3l = (e < 6) ? frb3[e] : 0.f;

    for (int i = rb * 25 + wv; i < rb * 25 + 25; i += 4) {
        f16x8 pra = *(const f16x8*)(Pb + i * 80 + hi * 16);
        f16x8 prb = *(const f16x8*)(Pb + i * 80 + 32 + hi * 16);
        float2 racc[8];
        #pragma unroll
        for (int p = 0; p < 8; ++p) { racc[p].x = 0.f; racc[p].y = 0.f; }

        int j = i + 1 + e; if (j >= 100) j -= 100;
        #pragma unroll
        for (int tb = 0; tb < 4; ++tb) {
            f16x8 psa = *(const f16x8*)(Pb + 8192 + j * 80 + hi * 16);
            f16x8 psb = *(const f16x8*)(Pb + 8192 + j * 80 + 32 + hi * 16);
            f16x8 h1a = pra + psa;
            f16x8 h1b = prb + psb;
            #pragma unroll
            for (int m = 0; m < 8; ++m) {
                h1a[m] = (h1a[m] > (f16)0.f) ? h1a[m] : (f16)0.f;
                h1b[m] = (h1b[m] > (f16)0.f) ? h1b[m] : (f16)0.f;
            }
            f32x16 c1 = __builtin_amdgcn_mfma_f32_32x32x16_f16(bf1a, h1a, Cb2, 0, 0, 0);
            c1 = __builtin_amdgcn_mfma_f32_32x32x16_f16(bf1b, h1b, c1, 0, 0, 0);

            // h2 rows live in regs 0..7: hi=0 -> rows 0..3,8..11; hi=1 -> 4..7,12..15.
            int pw0 = __builtin_bit_cast(int, __builtin_amdgcn_cvt_pkrtz(fmaxf(c1[0], 0.f), fmaxf(c1[1], 0.f)));
            int pw1 = __builtin_bit_cast(int, __builtin_amdgcn_cvt_pkrtz(fmaxf(c1[2], 0.f), fmaxf(c1[3], 0.f)));
            int pw2 = __builtin_bit_cast(int, __builtin_amdgcn_cvt_pkrtz(fmaxf(c1[4], 0.f), fmaxf(c1[5], 0.f)));
            int pw3 = __builtin_bit_cast(int, __builtin_amdgcn_cvt_pkrtz(fmaxf(c1[6], 0.f), fmaxf(c1[7], 0.f)));
            // exchange the half each partner needs (hi=0 sends pw2/pw3, hi=1 sends pw0/pw1)
            int s0 = hi ? pw0 : pw2;
            int s1 = hi ? pw1 : pw3;
            int r0 = __shfl_xor(s0, 32);
            int r1 = __shfl_xor(s1, 32);
            union { int w[4]; f16x8 v; } a2;
            a2.w[0] = hi ? r0  : pw0;
            a2.w[1] = hi ? r1  : pw1;
            a2.w[2] = hi ? pw2 : r0;
            a2.w[3] = hi ? pw3 : r1;

            f32x16 c2 = __builtin_amdgcn_mfma_f32_32x32x16_f16(a2.v, bf2, cz, 0, 0, 0);

            if (tb < 3) {
                #pragma unroll
                for (int p = 0; p < 8; ++p) {
                    racc[p].x += fmaxf(c2[2 * p]     + b3l, 0.f);
                    racc[p].y += fmaxf(c2[2 * p + 1] + b3l, 0.f);
                }
            } else {
                // valid senders 96..98 -> rows 0,1,2 (hi=0, regs 0..2)
                if (hi == 0) {
                    racc[0].x += fmaxf(c2[0] + b3l, 0.f);
                    racc[0].y += fmaxf(c2[1] + b3l, 0.f);
                    racc[1].x += fmaxf(c2[2] + b3l, 0.f);
                }
            }
            j += 32; if (j >= 100) j -= 100;
        }
        float s = 0.f;
        #pragma unroll
        for (int p = 0; p < 8; ++p) s += racc[p].x + racc[p].y;
        s += __shfl_xor(s, 32);
        if (hi == 0 && e < 6)
            agg[((size_t)b * NCONST + i) * 8 + e] = s;
    }
}

// ---------------- K3: fo MLP + fc + softmax ----------------
__global__ __launch_bounds__(512) void k3_out(
    const float* __restrict__ x,
    const float* __restrict__ bn_g, const float* __restrict__ bn_b,
    const float* __restrict__ bn_m, const float* __restrict__ bn_v,
    const float* __restrict__ agg_in,
    const float* __restrict__ fow1, const float* __restrict__ fob1,
    const float* __restrict__ fow2, const float* __restrict__ fob2,
    const float* __restrict__ fow3, const float* __restrict__ fob3,
    const float* __restrict__ fcw1, const float* __restrict__ fcb1,
    const float* __restrict__ fcw2, const float* __restrict__ fcb2,
    float* __restrict__ out)
{
    __shared__ float xs[NCONST][16];
    __shared__ float aggL[NCONST][8];
    __shared__ float foh1[NCONST][48];
    __shared__ float foh2[NCONST][24];
    __shared__ float fcin[8];
    __shared__ float hfc[48];
    __shared__ float logits[8];

    const int b   = blockIdx.x;
    const int tid = threadIdx.x;

    for (int idx = tid; idx < NCONST * 16; idx += 512) {
        int f = idx & 15;
        float s = bn_g[f] * rsqrtf(bn_v[f] + 1e-3f);
        xs[idx >> 4][f] = (x[(size_t)b * (NCONST * NF) + idx] - bn_m[f]) * s + bn_b[f];
    }
    for (int idx = tid; idx < NCONST * 6; idx += 512) {
        int n = idx / 6, c = idx - n * 6;
        aggL[n][c] = agg_in[(size_t)b * (NCONST * 8) + n * 8 + c];
    }
    if (tid < 8) fcin[tid] = 0.f;
    __syncthreads();

    // fo layer1 (100x45 dot-22)
    for (int idx = tid; idx < NCONST * 45; idx += 512) {
        int n = idx / 45, o = idx - n * 45;
        float acc = fob1[o];
        const float4* xv = (const float4*)(&xs[n][0]);
        #pragma unroll
        for (int q = 0; q < 4; ++q) {
            float4 xq = xv[q];
            acc = fmaf(xq.x, fow1[(4 * q + 0) * 45 + o], acc);
            acc = fmaf(xq.y, fow1[(4 * q + 1) * 45 + o], acc);
            acc = fmaf(xq.z, fow1[(4 * q + 2) * 45 + o], acc);
            acc = fmaf(xq.w, fow1[(4 * q + 3) * 45 + o], acc);
        }
        const float4 a0 = *(const float4*)(&aggL[n][0]);
        const float2 a1 = *(const float2*)(&aggL[n][4]);
        acc = fmaf(a0.x, fow1[16 * 45 + o], acc);
        acc = fmaf(a0.y, fow1[17 * 45 + o], acc);
        acc = fmaf(a0.z, fow1[18 * 45 + o], acc);
        acc = fmaf(a0.w, fow1[19 * 45 + o], acc);
        acc = fmaf(a1.x, fow1[20 * 45 + o], acc);
        acc = fmaf(a1.y, fow1[21 * 45 + o], acc);
        foh1[n][o] = fmaxf(acc, 0.f);
    }
    __syncthreads();

    // fo layer2 (100x22 dot-45)
    for (int idx = tid; idx < NCONST * 22; idx += 512) {
        int n = idx / 22, o = idx - n * 22;
        float acc = fob2[o];
        const float4* hv = (const float4*)(&foh1[n][0]);
        #pragma unroll
        for (int q = 0; q < 11; ++q) {
            float4 h4 = hv[q];
            acc = fmaf(h4.x, fow2[(4 * q + 0) * 22 + o], acc);
            acc = fmaf(h4.y, fow2[(4 * q + 1) * 22 + o], acc);
            acc = fmaf(h4.z, fow2[(4 * q + 2) * 22 + o], acc);
            acc = fmaf(h4.w, fow2[(4 * q + 3) * 22 + o], acc);
        }
        acc = fmaf(foh1[n][44], fow2[44 * 22 + o], acc);
        foh2[n][o] = fmaxf(acc, 0.f);
    }
    __syncthreads();

    // fo layer3 (100x6 dot-22) + node sum
    for (int idx = tid; idx < NCONST * 6; idx += 512) {
        int n = idx / 6, c = idx - n * 6;
        float acc = fob3[c];
        const float4* hv = (const float4*)(&foh2[n][0]);
        #pragma unroll
        for (int q = 0; q < 5; ++q) {
            float4 h4 = hv[q];
            acc = fmaf(h4.x, fow3[(4 * q + 0) * 6 + c], acc);
            acc = fmaf(h4.y, fow3[(4 * q + 1) * 6 + c], acc);
            acc = fmaf(h4.z, fow3[(4 * q + 2) * 6 + c], acc);
            acc = fmaf(h4.w, fow3[(4 * q + 3) * 6 + c], acc);
        }
        acc = fmaf(foh2[n][20], fow3[20 * 6 + c], acc);
        acc = fmaf(foh2[n][21], fow3[21 * 6 + c], acc);
        atomicAdd(&fcin[c], fmaxf(acc, 0.f));
    }
    __syncthreads();

    if (tid < 48) {
        float acc = fcb1[tid];
        #pragma unroll
        for (int k = 0; k < 6; ++k) acc = fmaf(fcin[k], fcw1[k * 48 + tid], acc);
        hfc[tid] = fmaxf(acc, 0.f);
    }
    __syncthreads();
    if (tid < 5) {
        float acc = fcb2[tid];
        #pragma unroll
        for (int k = 0; k < 48; ++k) acc = fmaf(hfc[k], fcw2[k * 5 + tid], acc);
        logits[tid] = acc;
    }
    __syncthreads();
    if (tid == 0) {
        float m = logits[0];
        #pragma unroll
        for (int c = 1; c < 5; ++c) m = fmaxf(m, logits[c]);
        float ex[5], sum = 0.f;
        #pragma unroll
        for (int c = 0; c < 5; ++c) { ex[c] = __expf(logits[c] - m); sum += ex[c]; }
        float inv = 1.f / sum;
        #pragma unroll
        for (int c = 0; c < 5; ++c) out[(size_t)b * 5 + c] = ex[c] * inv;
    }
}

extern "C" void kernel_launch(void* const* d_in, const int* in_sizes, int n_in,
                              void* d_out, int out_size, void* d_ws, size_t ws_size,
                              hipStream_t stream) {
    const float* x     = (const float*)d_in[0];
    const float* bn_g  = (const float*)d_in[1];
    const float* bn_b  = (const float*)d_in[2];
    const float* bn_m  = (const float*)d_in[3];
    const float* bn_v  = (const float*)d_in[4];
    const float* frw1  = (const float*)d_in[5];
    const float* frb1  = (const float*)d_in[6];
    const float* frw2  = (const float*)d_in[7];
    const float* frb2  = (const float*)d_in[8];
    const float* frw3  = (const float*)d_in[9];
    const float* frb3  = (const float*)d_in[10];
    const float* fow1  = (const float*)d_in[11];
    const float* fob1  = (const float*)d_in[12];
    const float* fow2  = (const float*)d_in[13];
    const float* fob2  = (const float*)d_in[14];
    const float* fow3  = (const float*)d_in[15];
    const float* fob3  = (const float*)d_in[16];
    const float* fcw1  = (const float*)d_in[17];
    const float* fcb1  = (const float*)d_in[18];
    const float* fcw2  = (const float*)d_in[19];
    const float* fcb2  = (const float*)d_in[20];

    const int B = in_sizes[0] / (NCONST * NF);   // 512

    f16*   prps = (f16*)d_ws;                                    // B * 16 KB
    float* agg  = (float*)((char*)d_ws + (size_t)B * 16384);     // B * 100 * 8 f32

    k1_proj<<<dim3(7, B), dim3(256), 0, stream>>>(
        x, bn_g, bn_b, bn_m, bn_v, frw1, frb1, prps);
    k2_edge<<<dim3(4, B), dim3(256), 0, stream>>>(
        prps, frw2, frb2, frw3, frb3, agg);
    k3_out<<<dim3(B), dim3(512), 0, stream>>>(
        x, bn_g, bn_b, bn_m, bn_v, agg,
        fow1, fob1, fow2, fob2, fow3, fob3,
        fcw1, fcb1, fcw2, fcb2, (float*)d_out);
}

// Round 9
// 67.920 us; speedup vs baseline: 1.4403x; 1.4403x over previous
//
#include <hip/hip_runtime.h>
#include <math.h>

#define NCONST 100
#define NF     16
#define BLK    512

typedef _Float16 f16;
typedef _Float16 f16x8 __attribute__((ext_vector_type(8)));
typedef _Float16 f16x4 __attribute__((ext_vector_type(4)));
typedef float    f32x16 __attribute__((ext_vector_type(16)));

// One block per batch element, 512 threads (8 waves), ~38.7 KB LDS.
// Edge phase (per wave): receiver i, 4 tiles of 32 senders, 32x32x16 MFMA.
//   - W2^T is the A-operand with b2 folded in as k=30 (Pr half-30 == 1.0,
//     Ps half-30 == 0, so h1[30] = relu(1) = 1 rides the bias through MFMA1).
//   - swapped MFMA1 -> lane holds h2 rows of its edge; 2 shfl_xor(32) + selects
//     redistribute into the MFMA2 A-fragment (HW-verified in R8).
//   - b3 folded as k2=15 of W3 (pw3 high half = 1.0 on hi=1 lanes).
//   - register accumulation, one plain store per receiver. No atomics.
// Pr/Ps rows = 80 B, 16B slots XOR-swizzled by (row>>3)&1 on write AND read:
// kills the 4-way ds_read_b128 bank conflict at stride-80 (2-way left = free).
// launch_bounds(512,4): VGPR cap 128 (R3 lesson: do NOT force higher occupancy;
// spill tripwire = FETCH_SIZE >> 2 MB).
__global__ __launch_bounds__(BLK, 4) void convint_fused(
    const float* __restrict__ x,
    const float* __restrict__ bn_g, const float* __restrict__ bn_b,
    const float* __restrict__ bn_m, const float* __restrict__ bn_v,
    const float* __restrict__ frw1, const float* __restrict__ frb1,
    const float* __restrict__ frw2, const float* __restrict__ frb2,
    const float* __restrict__ frw3, const float* __restrict__ frb3,
    const float* __restrict__ fow1, const float* __restrict__ fob1,
    const float* __restrict__ fow2, const float* __restrict__ fob2,
    const float* __restrict__ fow3, const float* __restrict__ fob3,
    const float* __restrict__ fcw1, const float* __restrict__ fcb1,
    const float* __restrict__ fcw2, const float* __restrict__ fcb2,
    float* __restrict__ out)
{
    __shared__ float xbn[NCONST][NF];   // 6.4 KB
    __shared__ float upool[7200];       // 28.8 KB multi-use
    __shared__ float aggF[NCONST * 8];  // 3.2 KB (6 used/row)
    __shared__ float fcin[8];
    __shared__ float hfc[48];
    __shared__ float logits[8];

    // Edge layout: Pr rows @ PrB + i*80 (f16, 40 halves), Ps @ PsB + j*80.
    char* const PrB = (char*)upool;           // 8000 B
    char* const PsB = PrB + 8000;             // 8000 B
    // fo overlay (edge data dead by then):
    float (*const foh1)[48] = (float (*)[48])upool;            // 100x48 (45 used)
    float (*const foh2)[24] = (float (*)[24])(upool + 4800);   // 100x24 (22 used)

    const int b   = blockIdx.x;
    const int tid = threadIdx.x;
    const float* xb = x + (size_t)b * (NCONST * NF);

    // ---- BatchNorm into LDS + init ----
    for (int idx = tid; idx < NCONST * NF; idx += BLK) {
        int f = idx & 15;
        float sc = rsqrtf(bn_v[f] + 1e-3f) * bn_g[f];
        xbn[idx >> 4][f] = (xb[idx] - bn_m[f]) * sc + bn_b[f];
    }
    if (tid < 8) fcin[tid] = 0.f;
    __syncthreads();

    // ---- Layer-1 projections -> swizzled f16 LDS ----
    // item = (n, sel, oq): 1600 items, 4 outputs each. b1 folded into Pr.
    // oq==7 writes halves 28..31: [o28, o29, (Pr?1:0), 0] -> bias-const + k-pad.
    for (int idx = tid; idx < 1600; idx += BLK) {
        int n   = idx >> 4;
        int rem = idx & 15;
        int sel = rem >> 3;
        int oq  = rem & 7;
        int o0  = oq * 4;

        float xs[16];
        {
            const float4* xv = (const float4*)(&xbn[n][0]);
            float4 x0 = xv[0], x1 = xv[1], x2 = xv[2], x3 = xv[3];
            xs[0]=x0.x; xs[1]=x0.y; xs[2]=x0.z; xs[3]=x0.w;
            xs[4]=x1.x; xs[5]=x1.y; xs[6]=x1.z; xs[7]=x1.w;
            xs[8]=x2.x; xs[9]=x2.y; xs[10]=x2.z; xs[11]=x2.w;
            xs[12]=x3.x; xs[13]=x3.y; xs[14]=x3.z; xs[15]=x3.w;
        }
        float acc0 = (!sel) ? frb1[o0 + 0] : 0.f;
        float acc1 = (!sel) ? frb1[o0 + 1] : 0.f;
        float acc2 = (!sel && oq < 7) ? frb1[o0 + 2] : 0.f;
        float acc3 = (!sel && oq < 7) ? frb1[o0 + 3] : 0.f;
        const float* wbase = frw1 + sel * 16 * 30;
        const int wcol2 = (oq < 7) ? o0 + 2 : 28;   // clamp keeps loads in-bounds
        #pragma unroll
        for (int f = 0; f < 16; ++f) {
            const float* wr = wbase + f * 30;
            float2 wa = *(const float2*)(wr + o0);
            float2 wb = *(const float2*)(wr + wcol2);
            acc0 = fmaf(xs[f], wa.x, acc0);
            acc1 = fmaf(xs[f], wa.y, acc1);
            acc2 = fmaf(xs[f], wb.x, acc2);
            acc3 = fmaf(xs[f], wb.y, acc3);
        }
        f16x4 hv;
        hv[0] = (f16)acc0;
        hv[1] = (f16)acc1;
        hv[2] = (oq < 7) ? (f16)acc2 : (sel ? (f16)0.f : (f16)1.f);  // half30: 1 in Pr, 0 in Ps
        hv[3] = (oq < 7) ? (f16)acc3 : (f16)0.f;                     // half31: 0
        int slot = oq >> 1;
        int sw = (slot & 2) | ((slot ^ (n >> 3)) & 1);               // XOR-swizzle bit0
        *(f16x4*)((sel ? PsB : PrB) + n * 80 + sw * 16 + (oq & 1) * 8) = hv;
    }
    __syncthreads();

    // ---- Edge phase ----
    {
        const int l  = tid & 63;
        const int wv = tid >> 6;      // wave 0..7
        const int e  = l & 31;
        const int hi = l >> 5;

        const int eC  = (e < 15) ? e : 14;
        const int eC3 = (e < 6)  ? e : 5;

        // Weight fragments (VGPR-resident; clamped loads, masked values).
        f16x8 bf1a, bf1b, bf2;
        #pragma unroll
        for (int m = 0; m < 8; ++m) {
            int ka  = hi * 8 + m;          // 0..15
            int kb_ = 16 + ka;             // 16..31
            float wa = frw2[ka * 15 + eC];
            float wb = (kb_ < 30) ? frw2[kb_ * 15 + eC] : frb2[eC];   // k=30 -> b2
            float w3 = (ka  < 15) ? frw3[ka * 6 + eC3]  : frb3[eC3];  // k2=15 -> b3
            bf1a[m] = (e < 15)              ? (f16)wa : (f16)0.f;
            bf1b[m] = (e < 15 && kb_ < 31)  ? (f16)wb : (f16)0.f;
            bf2[m]  = (e < 6)               ? (f16)w3 : (f16)0.f;
        }
        f32x16 cz;
        #pragma unroll
        for (int r = 0; r < 16; ++r) cz[r] = 0.f;

        for (int i = wv; i < NCONST; i += 8) {
            const int pi = (i >> 3) & 1;
            const char* prp = PrB + i * 80 + ((hi ^ pi) * 16);
            f16x8 pra = *(const f16x8*)prp;
            f16x8 prb = *(const f16x8*)(prp + 32);
            float2 r2[2];
            r2[0].x = 0.f; r2[0].y = 0.f; r2[1].x = 0.f; r2[1].y = 0.f;

            int j = i + 1 + e; if (j >= 100) j -= 100;
            #pragma unroll
            for (int tb = 0; tb < 4; ++tb) {
                const int pj = (j >> 3) & 1;
                const char* psp = PsB + j * 80 + ((hi ^ pj) * 16);
                f16x8 psa = *(const f16x8*)psp;
                f16x8 psb = *(const f16x8*)(psp + 32);
                f16x8 h1a = pra + psa;
                f16x8 h1b = prb + psb;
                #pragma unroll
                for (int m = 0; m < 8; ++m) {
                    h1a[m] = (h1a[m] > (f16)0.f) ? h1a[m] : (f16)0.f;
                    h1b[m] = (h1b[m] > (f16)0.f) ? h1b[m] : (f16)0.f;
                }
                // MFMA1 swapped: D1[o2][edge]; b2 rides k=30 (h1b[hi=1][m=6]==1).
                f32x16 c1 = __builtin_amdgcn_mfma_f32_32x32x16_f16(bf1a, h1a, cz, 0, 0, 0);
                c1 = __builtin_amdgcn_mfma_f32_32x32x16_f16(bf1b, h1b, c1, 0, 0, 0);

                // pack h2 (regs 0..7) with relu; k2=15 slot := 1.0 on hi=1 (b3 hook)
                float v7 = hi ? 1.0f : fmaxf(c1[7], 0.f);
                int pw0 = __builtin_bit_cast(int, __builtin_amdgcn_cvt_pkrtz(fmaxf(c1[0], 0.f), fmaxf(c1[1], 0.f)));
                int pw1 = __builtin_bit_cast(int, __builtin_amdgcn_cvt_pkrtz(fmaxf(c1[2], 0.f), fmaxf(c1[3], 0.f)));
                int pw2 = __builtin_bit_cast(int, __builtin_amdgcn_cvt_pkrtz(fmaxf(c1[4], 0.f), fmaxf(c1[5], 0.f)));
                int pw3 = __builtin_bit_cast(int, __builtin_amdgcn_cvt_pkrtz(fmaxf(c1[6], 0.f), v7));
                // redistribute to MFMA2 A-frag (verified R8 pattern)
                int s0 = hi ? pw0 : pw2;
                int s1 = hi ? pw1 : pw3;
                int r0 = __shfl_xor(s0, 32);
                int r1 = __shfl_xor(s1, 32);
                union { int w[4]; f16x8 v; } a2;
                a2.w[0] = hi ? r0  : pw0;
                a2.w[1] = hi ? r1  : pw1;
                a2.w[2] = hi ? pw2 : r0;
                a2.w[3] = hi ? pw3 : r1;

                f32x16 c2 = __builtin_amdgcn_mfma_f32_32x32x16_f16(a2.v, bf2, cz, 0, 0, 0);

                if (tb < 3) {
                    #pragma unroll
                    for (int p = 0; p < 8; ++p) {
                        r2[p & 1].x += fmaxf(c2[2 * p],     0.f);
                        r2[p & 1].y += fmaxf(c2[2 * p + 1], 0.f);
                    }
                } else if (hi == 0) {
                    // valid senders 96..98 -> D rows 0,1,2 (hi=0 regs 0,1,2)
                    r2[0].x += fmaxf(c2[0], 0.f);
                    r2[0].y += fmaxf(c2[1], 0.f);
                    r2[1].x += fmaxf(c2[2], 0.f);
                }
                j += 32; if (j >= 100) j -= 100;
            }
            float s = r2[0].x + r2[0].y + r2[1].x + r2[1].y;
            s += __shfl_xor(s, 32);
            if (hi == 0 && e < 6) aggF[i * 8 + e] = s;   // exclusive owner
        }
    }
    __syncthreads();

    // ---- fo layer1 (100x45 dot-22) ----
    for (int idx = tid; idx < NCONST * 45; idx += BLK) {
        int n = idx / 45, o = idx - n * 45;
        float acc = fob1[o];
        const float4* xv = (const float4*)(&xbn[n][0]);
        #pragma unroll
        for (int q = 0; q < 4; ++q) {
            float4 xq = xv[q];
            acc = fmaf(xq.x, fow1[(4 * q + 0) * 45 + o], acc);
            acc = fmaf(xq.y, fow1[(4 * q + 1) * 45 + o], acc);
            acc = fmaf(xq.z, fow1[(4 * q + 2) * 45 + o], acc);
            acc = fmaf(xq.w, fow1[(4 * q + 3) * 45 + o], acc);
        }
        const float4 a0 = *(const float4*)(&aggF[n * 8]);
        const float2 a1 = *(const float2*)(&aggF[n * 8 + 4]);
        acc = fmaf(a0.x, fow1[16 * 45 + o], acc);
        acc = fmaf(a0.y, fow1[17 * 45 + o], acc);
        acc = fmaf(a0.z, fow1[18 * 45 + o], acc);
        acc = fmaf(a0.w, fow1[19 * 45 + o], acc);
        acc = fmaf(a1.x, fow1[20 * 45 + o], acc);
        acc = fmaf(a1.y, fow1[21 * 45 + o], acc);
        foh1[n][o] = fmaxf(acc, 0.f);
    }
    __syncthreads();

    // ---- fo layer2 (100x22 dot-45) ----
    for (int idx = tid; idx < NCONST * 22; idx += BLK) {
        int n = idx / 22, o = idx - n * 22;
        float acc = fob2[o];
        const float4* hv = (const float4*)(&foh1[n][0]);
        #pragma unroll
        for (int q = 0; q < 11; ++q) {
            float4 h4 = hv[q];
            acc = fmaf(h4.x, fow2[(4 * q + 0) * 22 + o], acc);
            acc = fmaf(h4.y, fow2[(4 * q + 1) * 22 + o], acc);
            acc = fmaf(h4.z, fow2[(4 * q + 2) * 22 + o], acc);
            acc = fmaf(h4.w, fow2[(4 * q + 3) * 22 + o], acc);
        }
        acc = fmaf(foh1[n][44], fow2[44 * 22 + o], acc);
        foh2[n][o] = fmaxf(acc, 0.f);
    }
    __syncthreads();

    // ---- fo layer3 (100x6 dot-22) + node sum ----
    for (int idx = tid; idx < NCONST * 6; idx += BLK) {
        int n = idx / 6, c = idx - n * 6;
        float acc = fob3[c];
        const float4* hv = (const float4*)(&foh2[n][0]);
        #pragma unroll
        for (int q = 0; q < 5; ++q) {
            float4 h4 = hv[q];
            acc = fmaf(h4.x, fow3[(4 * q + 0) * 6 + c], acc);
            acc = fmaf(h4.y, fow3[(4 * q + 1) * 6 + c], acc);
            acc = fmaf(h4.z, fow3[(4 * q + 2) * 6 + c], acc);
            acc = fmaf(h4.w, fow3[(4 * q + 3) * 6 + c], acc);
        }
        acc = fmaf(foh2[n][20], fow3[20 * 6 + c], acc);
        acc = fmaf(foh2[n][21], fow3[21 * 6 + c], acc);
        atomicAdd(&fcin[c], fmaxf(acc, 0.f));
    }
    __syncthreads();

    // ---- fc: 6 -> 48 (relu) -> 5 -> softmax ----
    if (tid < 48) {
        float acc = fcb1[tid];
        #pragma unroll
        for (int k = 0; k < 6; ++k) acc = fmaf(fcin[k], fcw1[k * 48 + tid], acc);
        hfc[tid] = fmaxf(acc, 0.f);
    }
    __syncthreads();
    if (tid < 5) {
        float acc = fcb2[tid];
        #pragma unroll
        for (int k = 0; k < 48; ++k) acc = fmaf(hfc[k], fcw2[k * 5 + tid], acc);
        logits[tid] = acc;
    }
    __syncthreads();
    if (tid == 0) {
        float m = logits[0];
        #pragma unroll
        for (int c = 1; c < 5; ++c) m = fmaxf(m, logits[c]);
        float ex[5], sum = 0.f;
        #pragma unroll
        for (int c = 0; c < 5; ++c) { ex[c] = __expf(logits[c] - m); sum += ex[c]; }
        float inv = 1.f / sum;
        #pragma unroll
        for (int c = 0; c < 5; ++c) out[(size_t)b * 5 + c] = ex[c] * inv;
    }
}

extern "C" void kernel_launch(void* const* d_in, const int* in_sizes, int n_in,
                              void* d_out, int out_size, void* d_ws, size_t ws_size,
                              hipStream_t stream) {
    const float* x     = (const float*)d_in[0];
    const float* bn_g  = (const float*)d_in[1];
    const float* bn_b  = (const float*)d_in[2];
    const float* bn_m  = (const float*)d_in[3];
    const float* bn_v  = (const float*)d_in[4];
    const float* frw1  = (const float*)d_in[5];
    const float* frb1  = (const float*)d_in[6];
    const float* frw2  = (const float*)d_in[7];
    const float* frb2  = (const float*)d_in[8];
    const float* frw3  = (const float*)d_in[9];
    const float* frb3  = (const float*)d_in[10];
    const float* fow1  = (const float*)d_in[11];
    const float* fob1  = (const float*)d_in[12];
    const float* fow2  = (const float*)d_in[13];
    const float* fob2  = (const float*)d_in[14];
    const float* fow3  = (const float*)d_in[15];
    const float* fob3  = (const float*)d_in[16];
    const float* fcw1  = (const float*)d_in[17];
    const float* fcb1  = (const float*)d_in[18];
    const float* fcw2  = (const float*)d_in[19];
    const float* fcb2  = (const float*)d_in[20];

    const int B = in_sizes[0] / (NCONST * NF);   // 512

    convint_fused<<<dim3(B), dim3(BLK), 0, stream>>>(
        x, bn_g, bn_b, bn_m, bn_v,
        frw1, frb1, frw2, frb2, frw3, frb3,
        fow1, fob1, fow2, fob2, fow3, fob3,
        fcw1, fcb1, fcw2, fcb2,
        (float*)d_out);
}